// Round 4
// baseline (184.498 us; speedup 1.0000x reference)
//
#include <hip/hip_runtime.h>

static constexpr int OHW = 12, NSP = 144;

// ---------------------------------------------------------------------------
// build_T: gather x (4,256,14,14) -> T[n][k][i], n = b*144+oh*12+ow,
// k = (kh*3+kw)*32 + ic, i in [0,8). One float4 (4 consecutive i) per thread.
// ---------------------------------------------------------------------------
__global__ void build_T(const float* __restrict__ x, float4* __restrict__ T4) {
    const int g = blockIdx.x * 256 + threadIdx.x;   // [0, 576*576)
    const int n = g / 576;                          // 576 float4 per n
    const int q = g - n * 576;
    const int r = q << 2;                           // float offset in row
    const int k = r >> 3;
    const int i0 = r & 7;                           // 0 or 4
    const int ic = k & 31;
    const int kk = k >> 5;
    const int kh = kk / 3, kw = kk - kh * 3;
    const int b = n / NSP;
    const int rm = n - b * NSP;
    const int oh = rm / OHW, ow = rm - oh * OHW;
    const float* xp = x + (size_t)(b * 256 + ic * 8 + i0) * 196
                        + (oh + kh) * 14 + (ow + kw);
    float4 v;
    v.x = xp[0];
    v.y = xp[196];
    v.z = xp[392];
    v.w = xp[588];
    T4[g] = v;
}

__device__ __forceinline__ void fma4(float4& a, float s, const float4& w) {
    a.x = fmaf(s, w.x, a.x);
    a.y = fmaf(s, w.y, a.y);
    a.z = fmaf(s, w.z, a.z);
    a.w = fmaf(s, w.w, a.w);
}

__device__ __forceinline__ float4 shfl_xor4(const float4& v, int m) {
    float4 r;
    r.x = __shfl_xor(v.x, m);
    r.y = __shfl_xor(v.y, m);
    r.z = __shfl_xor(v.z, m);
    r.w = __shfl_xor(v.w, m);
    return r;
}

// ---------------------------------------------------------------------------
// caps_main: block = (o, 4 n). 512 threads = 8 waves.
// Phase 1: thread = (cg = tid&3, kg = tid>>2 in [0,128)); 3 k-chunks of 128;
//   each (k,cg) weight quad loaded by exactly ONE thread, amortized over 4 n.
//   Slab jj = k>>4; chunk j holds slabs s = jj-8j = wv; write addr base+lane.
// Phase 2: wave = (nn = wv>>1, h = wv&1); lane (cg, kgp) owns k = 16*(9h+pl)+kgp,
//   pl in [0,9). Per-lane P = 9 float4 (36 regs, half of R2 -> 6 waves/SIMD).
//   k-reduce: in-lane over pl + shfl_xor {4,8,16,32} + tiny LDS cross-half
//   exchange (iter-indexed buffers, 1 barrier/iter). c-reduce: shfl_xor {1,2}.
// ---------------------------------------------------------------------------
__global__ __launch_bounds__(512, 6)
void caps_main(const float4* __restrict__ T4, const float4* __restrict__ W4,
               float* __restrict__ out) {
    __shared__ float4 Pl[4 * 8 * 64];        // 32,768 B
    __shared__ float4 ExV[3][4][2][4];       // 1,536 B  (iter, nn, half, cg)
    __shared__ float  ExS[2][4][2];          // 64 B     (iter-1, nn, half)

    const int tid  = threadIdx.x;
    const int o    = blockIdx.y;
    const int nbase = blockIdx.x * 4;
    const int cg   = tid & 3;
    const int kg   = tid >> 2;               // [0,128)
    const int wv   = tid >> 6;               // [0,8)  == kg>>4
    const int lane = tid & 63;
    const int nn   = wv >> 1;                // phase-2 n
    const int h    = wv & 1;                 // phase-2 k-half

    float4 P[9];

    // -------- phase-1 producer for one k-chunk --------
    auto produce = [&](int k) {
        float4 w[8];
        const float4* wp = W4 + (size_t)(o * 288 + k) * 32 + cg;
        #pragma unroll
        for (int i = 0; i < 8; ++i) w[i] = wp[i * 4];
        #pragma unroll
        for (int m = 0; m < 4; ++m) {
            const float4* tp = T4 + (size_t)(nbase + m) * 576 + k * 2;
            const float4 t0 = tp[0];
            const float4 t1 = tp[1];
            float4 a = make_float4(0.f, 0.f, 0.f, 0.f);
            fma4(a, t0.x, w[0]); fma4(a, t0.y, w[1]);
            fma4(a, t0.z, w[2]); fma4(a, t0.w, w[3]);
            fma4(a, t1.x, w[4]); fma4(a, t1.y, w[5]);
            fma4(a, t1.z, w[6]); fma4(a, t1.w, w[7]);
            Pl[m * 512 + wv * 64 + lane] = a;   // addr = base + lane
        }
    };

    const float4* Pn = &Pl[nn * 512];

    // ---- chunk 0: k = kg, slabs jj 0..7 -> half 0 pl 0..7 ----
    produce(kg);
    __syncthreads();
    if (h == 0) {
        #pragma unroll
        for (int s = 0; s < 8; ++s) P[s] = Pn[s * 64 + lane];
    }
    __syncthreads();

    // ---- chunk 1: k = kg+128, slabs jj 8..15 -> h0 pl8 (s0), h1 pl0..6 (s1..7) ----
    produce(kg + 128);
    __syncthreads();
    if (h == 0) {
        P[8] = Pn[lane];
    } else {
        #pragma unroll
        for (int s = 1; s < 8; ++s) P[s - 1] = Pn[s * 64 + lane];
    }
    __syncthreads();

    // ---- chunk 2: k = kg+256 (valid kg<32), slabs jj 16,17 -> h1 pl 7,8 ----
    if (kg < 32) produce(kg + 256);
    __syncthreads();
    if (h == 1) {
        P[7] = Pn[lane];
        P[8] = Pn[64 + lane];
    }

    // -------- phase 2: dynamic routing --------
    float lj[9];
    #pragma unroll
    for (int pl = 0; pl < 9; ++pl) lj[pl] = 0.f;
    float4 vq = make_float4(0.f, 0.f, 0.f, 0.f);

    #pragma unroll
    for (int it = 0; it < 3; ++it) {
        float4 svU = make_float4(0.f, 0.f, 0.f, 0.f);
        float Sp = 0.f;
        if (it == 0) {
            #pragma unroll
            for (int pl = 0; pl < 9; ++pl) {
                svU.x += P[pl].x; svU.y += P[pl].y;
                svU.z += P[pl].z; svU.w += P[pl].w;
            }
        } else {
            #pragma unroll
            for (int pl = 0; pl < 9; ++pl) {
                const float e = __expf(lj[pl]);   // |lj| <~ 10: safe in fp32
                Sp += e;
                fma4(svU, e, P[pl]);
            }
        }
        #pragma unroll
        for (int m = 4; m < 64; m <<= 1) {
            const float4 t = shfl_xor4(svU, m);
            svU.x += t.x; svU.y += t.y; svU.z += t.z; svU.w += t.w;
            if (it != 0) Sp += __shfl_xor(Sp, m);
        }
        // cross-half exchange (iter-indexed buffers; one barrier per iter)
        if ((lane >> 2) == 0) {
            ExV[it][nn][h][cg] = svU;
            if (it != 0 && lane == 0) ExS[it - 1][nn][h] = Sp;
        }
        __syncthreads();
        const float4 t = ExV[it][nn][h ^ 1][cg];
        svU.x += t.x; svU.y += t.y; svU.z += t.z; svU.w += t.w;
        const float S = (it == 0) ? 288.0f : (Sp + ExS[it - 1][nn][h ^ 1]);
        const float invS = __frcp_rn(S);
        float4 s;
        s.x = svU.x * invS; s.y = svU.y * invS;
        s.z = svU.z * invS; s.w = svU.w * invS;
        float sq = s.x * s.x + s.y * s.y + s.z * s.z + s.w * s.w;
        sq += __shfl_xor(sq, 1);
        sq += __shfl_xor(sq, 2);
        const float scale = __fsqrt_rn(sq) / (1.0f + sq);
        vq.x = s.x * scale; vq.y = s.y * scale;
        vq.z = s.z * scale; vq.w = s.w * scale;

        if (it < 2) {
            #pragma unroll
            for (int pl = 0; pl < 9; ++pl) {
                float d = P[pl].x * vq.x + P[pl].y * vq.y +
                          P[pl].z * vq.z + P[pl].w * vq.w;
                d += __shfl_xor(d, 1);
                d += __shfl_xor(d, 2);
                lj[pl] += d;
            }
        }
    }

    // -------- store: half-0 waves, lanes kgp==0 write their c-quad --------
    if (h == 0 && (lane >> 2) == 0) {
        const int n = nbase + nn;
        const int b = n / NSP;
        const int rm = n - b * NSP;
        float* op = out + (size_t)(b * 512 + o * 16 + cg * 4) * NSP + rm;
        op[0 * NSP] = vq.x;
        op[1 * NSP] = vq.y;
        op[2 * NSP] = vq.z;
        op[3 * NSP] = vq.w;
    }
}

extern "C" void kernel_launch(void* const* d_in, const int* in_sizes, int n_in,
                              void* d_out, int out_size, void* d_ws, size_t ws_size,
                              hipStream_t stream) {
    const float* x  = (const float*)d_in[0];   // (4, 256, 14, 14)
    const float* wt = (const float*)d_in[1];   // (32, 288, 8, 16)
    float* out = (float*)d_out;                // (4, 512, 12, 12)
    float4* T4 = (float4*)d_ws;                // 576*2304 floats = 5.3 MB

    build_T<<<dim3(576 * 576 / 256), 256, 0, stream>>>(x, T4);
    caps_main<<<dim3(144, 32), 512, 0, stream>>>(T4, (const float4*)wt, out);
}

// Round 5
// 149.674 us; speedup vs baseline: 1.2327x; 1.2327x over previous
//
#include <hip/hip_runtime.h>

static constexpr int OHW = 12, NSP = 144;

// ---------------------------------------------------------------------------
// build_T: gather x (4,256,14,14) -> T[n][k][i], n = b*144+oh*12+ow,
// k = (kh*3+kw)*32 + ic, i in [0,8). One float4 (4 consecutive i) per thread.
// ---------------------------------------------------------------------------
__global__ void build_T(const float* __restrict__ x, float4* __restrict__ T4) {
    const int g = blockIdx.x * 256 + threadIdx.x;   // [0, 576*576)
    const int n = g / 576;                          // 576 float4 per n
    const int q = g - n * 576;
    const int r = q << 2;                           // float offset in row
    const int k = r >> 3;
    const int i0 = r & 7;                           // 0 or 4
    const int ic = k & 31;
    const int kk = k >> 5;
    const int kh = kk / 3, kw = kk - kh * 3;
    const int b = n / NSP;
    const int rm = n - b * NSP;
    const int oh = rm / OHW, ow = rm - oh * OHW;
    const float* xp = x + (size_t)(b * 256 + ic * 8 + i0) * 196
                        + (oh + kh) * 14 + (ow + kw);
    float4 v;
    v.x = xp[0];
    v.y = xp[196];
    v.z = xp[392];
    v.w = xp[588];
    T4[g] = v;
}

__device__ __forceinline__ void fma4(float4& a, float s, const float4& w) {
    a.x = fmaf(s, w.x, a.x);
    a.y = fmaf(s, w.y, a.y);
    a.z = fmaf(s, w.z, a.z);
    a.w = fmaf(s, w.w, a.w);
}

__device__ __forceinline__ float4 shfl_xor4(const float4& v, int m) {
    float4 r;
    r.x = __shfl_xor(v.x, m);
    r.y = __shfl_xor(v.y, m);
    r.z = __shfl_xor(v.z, m);
    r.w = __shfl_xor(v.w, m);
    return r;
}

// ---------------------------------------------------------------------------
// caps_main: block = (o, 4 n). 512 threads = 8 waves.
// Identical structure to Round 4; ONLY change: __launch_bounds__(512, 4)
// (R4's (512,6) capped VGPRs at ~85 -> P[] spilled to scratch -> 201 MB HBM
// writes. 4 waves/EU caps at 128 VGPRs; working set ~100 fits, no spill.)
// ---------------------------------------------------------------------------
__global__ __launch_bounds__(512, 4)
void caps_main(const float4* __restrict__ T4, const float4* __restrict__ W4,
               float* __restrict__ out) {
    __shared__ float4 Pl[4 * 8 * 64];        // 32,768 B
    __shared__ float4 ExV[3][4][2][4];       // 1,536 B  (iter, nn, half, cg)
    __shared__ float  ExS[2][4][2];          // 64 B     (iter-1, nn, half)

    const int tid  = threadIdx.x;
    const int o    = blockIdx.y;
    const int nbase = blockIdx.x * 4;
    const int cg   = tid & 3;
    const int kg   = tid >> 2;               // [0,128)
    const int wv   = tid >> 6;               // [0,8)  == kg>>4
    const int lane = tid & 63;
    const int nn   = wv >> 1;                // phase-2 n
    const int h    = wv & 1;                 // phase-2 k-half

    float4 P[9];

    // -------- phase-1 producer for one k-chunk --------
    auto produce = [&](int k) {
        float4 w[8];
        const float4* wp = W4 + (size_t)(o * 288 + k) * 32 + cg;
        #pragma unroll
        for (int i = 0; i < 8; ++i) w[i] = wp[i * 4];
        #pragma unroll
        for (int m = 0; m < 4; ++m) {
            const float4* tp = T4 + (size_t)(nbase + m) * 576 + k * 2;
            const float4 t0 = tp[0];
            const float4 t1 = tp[1];
            float4 a = make_float4(0.f, 0.f, 0.f, 0.f);
            fma4(a, t0.x, w[0]); fma4(a, t0.y, w[1]);
            fma4(a, t0.z, w[2]); fma4(a, t0.w, w[3]);
            fma4(a, t1.x, w[4]); fma4(a, t1.y, w[5]);
            fma4(a, t1.z, w[6]); fma4(a, t1.w, w[7]);
            Pl[m * 512 + wv * 64 + lane] = a;   // addr = base + lane
        }
    };

    const float4* Pn = &Pl[nn * 512];

    // ---- chunk 0: k = kg, slabs jj 0..7 -> half 0 pl 0..7 ----
    produce(kg);
    __syncthreads();
    if (h == 0) {
        #pragma unroll
        for (int s = 0; s < 8; ++s) P[s] = Pn[s * 64 + lane];
    }
    __syncthreads();

    // ---- chunk 1: k = kg+128, slabs jj 8..15 -> h0 pl8 (s0), h1 pl0..6 (s1..7) ----
    produce(kg + 128);
    __syncthreads();
    if (h == 0) {
        P[8] = Pn[lane];
    } else {
        #pragma unroll
        for (int s = 1; s < 8; ++s) P[s - 1] = Pn[s * 64 + lane];
    }
    __syncthreads();

    // ---- chunk 2: k = kg+256 (valid kg<32), slabs jj 16,17 -> h1 pl 7,8 ----
    if (kg < 32) produce(kg + 256);
    __syncthreads();
    if (h == 1) {
        P[7] = Pn[lane];
        P[8] = Pn[64 + lane];
    }

    // -------- phase 2: dynamic routing --------
    float lj[9];
    #pragma unroll
    for (int pl = 0; pl < 9; ++pl) lj[pl] = 0.f;
    float4 vq = make_float4(0.f, 0.f, 0.f, 0.f);

    #pragma unroll
    for (int it = 0; it < 3; ++it) {
        float4 svU = make_float4(0.f, 0.f, 0.f, 0.f);
        float Sp = 0.f;
        if (it == 0) {
            #pragma unroll
            for (int pl = 0; pl < 9; ++pl) {
                svU.x += P[pl].x; svU.y += P[pl].y;
                svU.z += P[pl].z; svU.w += P[pl].w;
            }
        } else {
            #pragma unroll
            for (int pl = 0; pl < 9; ++pl) {
                const float e = __expf(lj[pl]);   // |lj| <~ 10: safe in fp32
                Sp += e;
                fma4(svU, e, P[pl]);
            }
        }
        #pragma unroll
        for (int m = 4; m < 64; m <<= 1) {
            const float4 t = shfl_xor4(svU, m);
            svU.x += t.x; svU.y += t.y; svU.z += t.z; svU.w += t.w;
            if (it != 0) Sp += __shfl_xor(Sp, m);
        }
        // cross-half exchange (iter-indexed buffers; one barrier per iter)
        if ((lane >> 2) == 0) {
            ExV[it][nn][h][cg] = svU;
            if (it != 0 && lane == 0) ExS[it - 1][nn][h] = Sp;
        }
        __syncthreads();
        const float4 t = ExV[it][nn][h ^ 1][cg];
        svU.x += t.x; svU.y += t.y; svU.z += t.z; svU.w += t.w;
        const float S = (it == 0) ? 288.0f : (Sp + ExS[it - 1][nn][h ^ 1]);
        const float invS = __frcp_rn(S);
        float4 s;
        s.x = svU.x * invS; s.y = svU.y * invS;
        s.z = svU.z * invS; s.w = svU.w * invS;
        float sq = s.x * s.x + s.y * s.y + s.z * s.z + s.w * s.w;
        sq += __shfl_xor(sq, 1);
        sq += __shfl_xor(sq, 2);
        const float scale = __fsqrt_rn(sq) / (1.0f + sq);
        vq.x = s.x * scale; vq.y = s.y * scale;
        vq.z = s.z * scale; vq.w = s.w * scale;

        if (it < 2) {
            #pragma unroll
            for (int pl = 0; pl < 9; ++pl) {
                float d = P[pl].x * vq.x + P[pl].y * vq.y +
                          P[pl].z * vq.z + P[pl].w * vq.w;
                d += __shfl_xor(d, 1);
                d += __shfl_xor(d, 2);
                lj[pl] += d;
            }
        }
    }

    // -------- store: half-0 waves, lanes kgp==0 write their c-quad --------
    if (h == 0 && (lane >> 2) == 0) {
        const int n = nbase + nn;
        const int b = n / NSP;
        const int rm = n - b * NSP;
        float* op = out + (size_t)(b * 512 + o * 16 + cg * 4) * NSP + rm;
        op[0 * NSP] = vq.x;
        op[1 * NSP] = vq.y;
        op[2 * NSP] = vq.z;
        op[3 * NSP] = vq.w;
    }
}

extern "C" void kernel_launch(void* const* d_in, const int* in_sizes, int n_in,
                              void* d_out, int out_size, void* d_ws, size_t ws_size,
                              hipStream_t stream) {
    const float* x  = (const float*)d_in[0];   // (4, 256, 14, 14)
    const float* wt = (const float*)d_in[1];   // (32, 288, 8, 16)
    float* out = (float*)d_out;                // (4, 512, 12, 12)
    float4* T4 = (float4*)d_ws;                // 576*2304 floats = 5.3 MB

    build_T<<<dim3(576 * 576 / 256), 256, 0, stream>>>(x, T4);
    caps_main<<<dim3(144, 32), 512, 0, stream>>>(T4, (const float4*)wt, out);
}

// Round 6
// 126.642 us; speedup vs baseline: 1.4568x; 1.1819x over previous
//
#include <hip/hip_runtime.h>

static constexpr int OHW = 12, NSP = 144;

// ---------------------------------------------------------------------------
// build_T: gather x (4,256,14,14) -> T[n][k][i], n = b*144+oh*12+ow,
// k = (kh*3+kw)*32 + ic, i in [0,8). One float4 (4 consecutive i) per thread.
// ---------------------------------------------------------------------------
__global__ void build_T(const float* __restrict__ x, float4* __restrict__ T4) {
    const int g = blockIdx.x * 256 + threadIdx.x;   // [0, 576*576)
    const int n = g / 576;                          // 576 float4 per n
    const int q = g - n * 576;
    const int r = q << 2;                           // float offset in row
    const int k = r >> 3;
    const int i0 = r & 7;                           // 0 or 4
    const int ic = k & 31;
    const int kk = k >> 5;
    const int kh = kk / 3, kw = kk - kh * 3;
    const int b = n / NSP;
    const int rm = n - b * NSP;
    const int oh = rm / OHW, ow = rm - oh * OHW;
    const float* xp = x + (size_t)(b * 256 + ic * 8 + i0) * 196
                        + (oh + kh) * 14 + (ow + kw);
    float4 v;
    v.x = xp[0];
    v.y = xp[196];
    v.z = xp[392];
    v.w = xp[588];
    T4[g] = v;
}

__device__ __forceinline__ void fma4(float4& a, float s, const float4& w) {
    a.x = fmaf(s, w.x, a.x);
    a.y = fmaf(s, w.y, a.y);
    a.z = fmaf(s, w.z, a.z);
    a.w = fmaf(s, w.w, a.w);
}

__device__ __forceinline__ float4 shfl_xor4(const float4& v, int m) {
    float4 r;
    r.x = __shfl_xor(v.x, m);
    r.y = __shfl_xor(v.y, m);
    r.z = __shfl_xor(v.z, m);
    r.w = __shfl_xor(v.w, m);
    return r;
}

// ---------------------------------------------------------------------------
// caps_main: block = (o, 8 n). 512 threads = 8 waves. R2 structure with
// NB=8 (weight L2 stream halved to 340 MB; each (k,cg) weight quad loaded
// by ONE thread, amortized over 8 n).
// Phase 1: thread = (cg = tid&3, kg = tid>>2 in [0,128)); chunks k = kg,
//   kg+128, and tail kg+256 (kg<32). Slab jj = k>>4; slab-local = wv;
//   write addr = base + lane (conflict-free b128 both sides).
// Phase 2: wave = one n (R2 routing, unchanged): lane (cg,kgp) owns
//   k = kgp + 16*jj, jj in [0,18); P[18] float4 in regs; k-reduce
//   shfl_xor {4,8,16,32}; c-reduce shfl_xor {1,2} (DPP quad-perm).
// __launch_bounds__(512,3): ~170-reg cap; working set ~130 -> no spill
// (R4 spilled at 85-cap, R5 at 128-cap).
// ---------------------------------------------------------------------------
__global__ __launch_bounds__(512, 3)
void caps_main(const float4* __restrict__ T4, const float4* __restrict__ W4,
               float* __restrict__ out) {
    __shared__ float4 Pl[8 * 8 * 64];        // 65,536 B -> 2 blocks/CU

    const int tid   = threadIdx.x;
    const int o     = blockIdx.y;
    const int nbase = blockIdx.x * 8;
    const int cg    = tid & 3;
    const int kg    = tid >> 2;              // [0,128)
    const int wv    = tid >> 6;              // [0,8)  == kg>>4
    const int lane  = tid & 63;

    float4 P[18];

    // -------- phase-1 producer for one k (8-n amortized weight load) --------
    auto produce = [&](int k) {
        float4 w[8];
        const float4* wp = W4 + (size_t)(o * 288 + k) * 32 + cg;
        #pragma unroll
        for (int i = 0; i < 8; ++i) w[i] = wp[i * 4];
        #pragma unroll
        for (int m = 0; m < 8; ++m) {
            const float4* tp = T4 + (size_t)(nbase + m) * 576 + k * 2;
            const float4 t0 = tp[0];
            const float4 t1 = tp[1];
            float4 a = make_float4(0.f, 0.f, 0.f, 0.f);
            fma4(a, t0.x, w[0]); fma4(a, t0.y, w[1]);
            fma4(a, t0.z, w[2]); fma4(a, t0.w, w[3]);
            fma4(a, t1.x, w[4]); fma4(a, t1.y, w[5]);
            fma4(a, t1.z, w[6]); fma4(a, t1.w, w[7]);
            Pl[m * 512 + wv * 64 + lane] = a;   // addr = base + lane
        }
    };

    const float4* Pn = &Pl[wv * 512];        // phase-2 read base (wave = n)

    // ---- chunk 0: k = kg, slabs jj 0..7 ----
    produce(kg);
    __syncthreads();
    #pragma unroll
    for (int s = 0; s < 8; ++s) P[s] = Pn[s * 64 + lane];
    __syncthreads();

    // ---- chunk 1: k = kg+128, slabs jj 8..15 ----
    produce(kg + 128);
    __syncthreads();
    #pragma unroll
    for (int s = 0; s < 8; ++s) P[8 + s] = Pn[s * 64 + lane];
    __syncthreads();

    // ---- chunk 2 (tail): k = kg+256, kg<32, slabs jj 16,17 ----
    if (kg < 32) produce(kg + 256);
    __syncthreads();
    P[16] = Pn[lane];
    P[17] = Pn[64 + lane];

    // -------- phase 2: dynamic routing (wave = n), R2-identical --------
    float lj[18];
    #pragma unroll
    for (int jj = 0; jj < 18; ++jj) lj[jj] = 0.f;
    float4 vq = make_float4(0.f, 0.f, 0.f, 0.f);

    #pragma unroll
    for (int it = 0; it < 3; ++it) {
        float4 svU = make_float4(0.f, 0.f, 0.f, 0.f);
        float S;
        if (it == 0) {
            #pragma unroll
            for (int jj = 0; jj < 18; ++jj) {
                svU.x += P[jj].x; svU.y += P[jj].y;
                svU.z += P[jj].z; svU.w += P[jj].w;
            }
            #pragma unroll
            for (int m = 4; m < 64; m <<= 1) {
                const float4 t = shfl_xor4(svU, m);
                svU.x += t.x; svU.y += t.y; svU.z += t.z; svU.w += t.w;
            }
            S = 288.0f;
        } else {
            S = 0.f;
            #pragma unroll
            for (int jj = 0; jj < 18; ++jj) {
                const float e = __expf(lj[jj]);   // |lj| <~ 10: safe in fp32
                S += e;
                fma4(svU, e, P[jj]);
            }
            #pragma unroll
            for (int m = 4; m < 64; m <<= 1) {
                const float4 t = shfl_xor4(svU, m);
                svU.x += t.x; svU.y += t.y; svU.z += t.z; svU.w += t.w;
                S += __shfl_xor(S, m);
            }
        }
        const float invS = __frcp_rn(S);
        float4 s;
        s.x = svU.x * invS; s.y = svU.y * invS;
        s.z = svU.z * invS; s.w = svU.w * invS;
        float sq = s.x * s.x + s.y * s.y + s.z * s.z + s.w * s.w;
        sq += __shfl_xor(sq, 1);
        sq += __shfl_xor(sq, 2);
        const float scale = __fsqrt_rn(sq) / (1.0f + sq);
        vq.x = s.x * scale; vq.y = s.y * scale;
        vq.z = s.z * scale; vq.w = s.w * scale;

        if (it < 2) {
            #pragma unroll
            for (int jj = 0; jj < 18; ++jj) {
                float d = P[jj].x * vq.x + P[jj].y * vq.y +
                          P[jj].z * vq.z + P[jj].w * vq.w;
                d += __shfl_xor(d, 1);
                d += __shfl_xor(d, 2);
                lj[jj] += d;
            }
        }
    }

    // -------- store: lanes kgp==0 write their c-quad --------
    if ((lane >> 2) == 0) {
        const int n = nbase + wv;
        const int b = n / NSP;
        const int rm = n - b * NSP;
        float* op = out + (size_t)(b * 512 + o * 16 + cg * 4) * NSP + rm;
        op[0 * NSP] = vq.x;
        op[1 * NSP] = vq.y;
        op[2 * NSP] = vq.z;
        op[3 * NSP] = vq.w;
    }
}

extern "C" void kernel_launch(void* const* d_in, const int* in_sizes, int n_in,
                              void* d_out, int out_size, void* d_ws, size_t ws_size,
                              hipStream_t stream) {
    const float* x  = (const float*)d_in[0];   // (4, 256, 14, 14)
    const float* wt = (const float*)d_in[1];   // (32, 288, 8, 16)
    float* out = (float*)d_out;                // (4, 512, 12, 12)
    float4* T4 = (float4*)d_ws;                // 576*2304 floats = 5.3 MB

    build_T<<<dim3(576 * 576 / 256), 256, 0, stream>>>(x, T4);
    caps_main<<<dim3(72, 32), 512, 0, stream>>>(T4, (const float4*)wt, out);
}